// Round 3
// baseline (484.222 us; speedup 1.0000x reference)
//
#include <hip/hip_runtime.h>
#include <hip/hip_cooperative_groups.h>

namespace cg = cooperative_groups;

#define B 8
#define T 512
#define TEMP_IN 32
#define STAT_IN 16
#define TEMP_H 64
#define STAT_H 32
#define ATTN_H 32
#define N_CLS 2
#define BN_INV 0.99999500003749969f
#define R 8          // query rows per attention tile
#define GRID (B * (T / R))   // 512 blocks

struct KP {
    const float *x_temp, *x_stat, *t;
    const int* lengths;
    const float *aw0, *ab0, *ag, *abeta, *aw1, *ab1;
    const float *tw, *tb, *tg, *tbeta;
    const float *sw, *sb, *sg, *sbeta;
    const float *lw_t, *lb_t, *lg_t, *lbeta_t;
    const float *lw_s, *lb_s, *lg_s, *lbeta_s;
    const float *cw, *cb;
    float *XL, *XT, *out, *outmax;
};

__device__ __forceinline__ float lrelu(float x) {
    return fmaxf(x, 0.f) + 0.01f * fminf(x, 0.f);
}
__device__ __forceinline__ float wave_max(float x) {
    #pragma unroll
    for (int o = 32; o > 0; o >>= 1) x = fmaxf(x, __shfl_xor(x, o));
    return x;
}
__device__ __forceinline__ float wave_sum(float x) {
    #pragma unroll
    for (int o = 32; o > 0; o >>= 1) x += __shfl_xor(x, o);
    return x;
}

struct Shm {
    float att[R][T];                 // 16 KB
    float xi[R][TEMP_H];             // 2 KB
    float part[4][R][TEMP_H];        // 8 KB
    float t_s[T];                    // 2 KB
    float s_w[5 * ATTN_H + 1];       // temp-MLP weights
    float xs_own[3][STAT_H];         // x_s chain for this block's batch
    float hbuf[4][TEMP_H + STAT_H];
    float xr[4][TEMP_IN];
    float s_cw[(TEMP_H + STAT_H) * N_CLS];
    float rb[4], r0[4], r1[4];
    int   ri[4];
};

// ---- MLP stage (96->64): src rows (+ xs concat) -> dst, masked
__device__ __forceinline__ void mlp_stage(const KP& P, Shm& S, const float* src, float* dst,
                                          const float* lw, const float* lb, const float* lg,
                                          const float* lbeta, const float* xs,
                                          int b, int tile, int len, int tid, bool front) {
    int g = tid >> 6, c = tid & 63;
    for (int p = 0; p < 2; ++p) {
        int r = p * 4 + g;
        int i = tile * 8 + r;
        int row = b * T + i;
        if (front) {
            if (c < TEMP_IN) S.xr[g][c] = P.x_temp[row * TEMP_IN + c];
            __syncthreads();
            float acc = P.tb[c];
            #pragma unroll
            for (int k = 0; k < TEMP_IN; ++k) acc += S.xr[g][k] * P.tw[k * TEMP_H + c];
            acc = acc * (P.tg[c] * BN_INV) + P.tbeta[c];
            S.hbuf[g][c] = lrelu(acc);
        } else {
            S.hbuf[g][c] = src[(size_t)row * TEMP_H + c];
        }
        if (c < STAT_H) S.hbuf[g][TEMP_H + c] = xs[c];
        __syncthreads();
        float a2 = lb[c];
        #pragma unroll
        for (int k = 0; k < TEMP_H + STAT_H; ++k) a2 += S.hbuf[g][k] * lw[k * TEMP_H + c];
        a2 = a2 * (lg[c] * BN_INV) + lbeta[c];
        a2 = lrelu(a2);
        dst[(size_t)row * TEMP_H + c] = (i < len) ? a2 : 0.f;
        __syncthreads();
    }
}

// ---- attention stage: qk softmax + recomputed temp softmax, PV
__device__ __forceinline__ void attn_stage(const KP& P, Shm& S, const float* src, float* dst,
                                           float inv_dt, int b, int tile, int len,
                                           int tid, int lane, int wave) {
    // load own query rows
    for (int idx = tid; idx < R * TEMP_H; idx += 256)
        S.xi[idx >> 6][idx & 63] = src[((size_t)(b * T + tile * 8 + (idx >> 6))) * TEMP_H + (idx & 63)];
    __syncthreads();
    // phase 1: qk
    for (int j = tid; j < T; j += 256) {
        const float4* xj4 = reinterpret_cast<const float4*>(&src[((size_t)(b * T + j)) * TEMP_H]);
        float acc[R];
        #pragma unroll
        for (int r = 0; r < R; ++r) acc[r] = 0.f;
        #pragma unroll
        for (int c4 = 0; c4 < TEMP_H / 4; ++c4) {
            float4 xv = xj4[c4];
            #pragma unroll
            for (int r = 0; r < R; ++r) {
                acc[r] += S.xi[r][c4 * 4 + 0] * xv.x;
                acc[r] += S.xi[r][c4 * 4 + 1] * xv.y;
                acc[r] += S.xi[r][c4 * 4 + 2] * xv.z;
                acc[r] += S.xi[r][c4 * 4 + 3] * xv.w;
            }
        }
        #pragma unroll
        for (int r = 0; r < R; ++r) S.att[r][j] = acc[r] * 0.125f;
    }
    __syncthreads();
    // phase 2: per-row softmax(qk) + temp-attn recompute + combine
    float ab1v = S.s_w[5 * ATTN_H];
    for (int rr = 0; rr < 2; ++rr) {
        int r = wave + rr * 4;
        int i = tile * 8 + r;
        float ti = S.t_s[i];
        float v[8], dtq[8];
        float m = -1e30f;
        #pragma unroll
        for (int q = 0; q < 8; ++q) {
            int j = lane + q * 64;
            v[q] = S.att[r][j];
            m = fmaxf(m, v[q]);
            dtq[q] = (S.t_s[j] - ti) * inv_dt;
        }
        m = wave_max(m);
        float s = 0.f;
        #pragma unroll
        for (int q = 0; q < 8; ++q) { v[q] = expf(v[q] - m); s += v[q]; }
        s = wave_sum(s);
        float invs = 1.0f / s;
        // temp logits (k-outer: 5 LDS broadcasts per k, 8 FMA chains)
        float a[8];
        #pragma unroll
        for (int q = 0; q < 8; ++q) a[q] = ab1v;
        #pragma unroll 4
        for (int k = 0; k < ATTN_H; ++k) {
            float w0k = S.s_w[k];
            float b0k = S.s_w[ATTN_H + k];
            float gk  = S.s_w[2 * ATTN_H + k];
            float bbk = S.s_w[3 * ATTN_H + k];
            float w1k = S.s_w[4 * ATTN_H + k];
            #pragma unroll
            for (int q = 0; q < 8; ++q) {
                float h = dtq[q] * w0k + b0k;
                h = h * gk + bbk;
                h = fmaxf(h, 0.f) + 0.01f * fminf(h, 0.f);
                a[q] += h * w1k;
            }
        }
        float m2 = -1e30f;
        #pragma unroll
        for (int q = 0; q < 8; ++q) {
            int j = lane + q * 64;
            a[q] = (j < len) ? a[q] : -9e8f;
            m2 = fmaxf(m2, a[q]);
        }
        m2 = wave_max(m2);
        float s2 = 0.f;
        #pragma unroll
        for (int q = 0; q < 8; ++q) { a[q] = expf(a[q] - m2); s2 += a[q]; }
        s2 = wave_sum(s2);
        float inv2 = 1.0f / s2;
        #pragma unroll
        for (int q = 0; q < 8; ++q) {
            int j = lane + q * 64;
            S.att[r][j] = (j < len) ? (v[q] * invs + a[q] * inv2) : 0.f;
        }
    }
    __syncthreads();
    // phase 3: PV
    float acc2[R];
    #pragma unroll
    for (int r = 0; r < R; ++r) acc2[r] = 0.f;
    for (int j = wave * 128; j < wave * 128 + 128; ++j) {
        float xv = src[((size_t)(b * T + j)) * TEMP_H + lane];
        #pragma unroll
        for (int r = 0; r < R; ++r) acc2[r] += S.att[r][j] * xv;
    }
    #pragma unroll
    for (int r = 0; r < R; ++r) S.part[wave][r][lane] = acc2[r];
    __syncthreads();
    for (int idx = tid; idx < R * TEMP_H; idx += 256) {
        int r = idx >> 6, cc = idx & 63;
        float sum = S.part[0][r][cc] + S.part[1][r][cc] + S.part[2][r][cc] + S.part[3][r][cc];
        int i = tile * 8 + r;
        dst[((size_t)(b * T + i)) * TEMP_H + cc] = (i < len) ? sum : 0.f;
    }
    __syncthreads();
}

// ---- epilogue: classifier + masked argmax
__device__ __forceinline__ void out_stage(const KP& P, Shm& S, int b, int tile, int len, int tid) {
    if (tile != 0) return;
    if (tid < (TEMP_H + STAT_H) * N_CLS) S.s_cw[tid] = P.cw[tid];
    __syncthreads();
    float cb0 = P.cb[0], cb1 = P.cb[1];
    float best = -3e30f, bv0 = 0.f, bv1 = 0.f;
    int besti = 0x7fffffff;
    for (int i = tid; i < T; i += 256) {
        const float* xrow = &P.XT[((size_t)(b * T + i)) * TEMP_H];
        float o0 = cb0, o1 = cb1;
        #pragma unroll
        for (int k = 0; k < TEMP_H; ++k) {
            float v = xrow[k];
            o0 += v * S.s_cw[k * 2]; o1 += v * S.s_cw[k * 2 + 1];
        }
        #pragma unroll
        for (int k = 0; k < STAT_H; ++k) {
            float v = S.xs_own[2][k];
            o0 += v * S.s_cw[(TEMP_H + k) * 2]; o1 += v * S.s_cw[(TEMP_H + k) * 2 + 1];
        }
        bool valid = i < len;
        if (!valid) { o0 = 0.f; o1 = 0.f; }
        P.out[((size_t)(b * T + i)) * N_CLS] = o0;
        P.out[((size_t)(b * T + i)) * N_CLS + 1] = o1;
        float diff = valid ? (o1 - o0) : -1e30f;
        if (diff > best || (diff == best && i < besti)) { best = diff; bv0 = o0; bv1 = o1; besti = i; }
    }
    #pragma unroll
    for (int o = 32; o > 0; o >>= 1) {
        float ob = __shfl_xor(best, o), o0s = __shfl_xor(bv0, o), o1s = __shfl_xor(bv1, o);
        int oi = __shfl_xor(besti, o);
        if (ob > best || (ob == best && oi < besti)) { best = ob; bv0 = o0s; bv1 = o1s; besti = oi; }
    }
    if ((tid & 63) == 0) { S.rb[tid >> 6] = best; S.r0[tid >> 6] = bv0; S.r1[tid >> 6] = bv1; S.ri[tid >> 6] = besti; }
    __syncthreads();
    if (tid == 0) {
        for (int w = 1; w < 4; ++w) {
            if (S.rb[w] > best || (S.rb[w] == best && S.ri[w] < besti)) {
                best = S.rb[w]; bv0 = S.r0[w]; bv1 = S.r1[w]; besti = S.ri[w];
            }
        }
        P.outmax[b * 2] = bv0;
        P.outmax[b * 2 + 1] = bv1;
    }
}

// ---- shared preamble: weights to LDS, t row, x_s chain, dt max
__device__ __forceinline__ float preamble(const KP& P, Shm& S, int b, int tid, int* plen) {
    if (tid < ATTN_H) {
        S.s_w[tid]              = P.aw0[tid];
        S.s_w[ATTN_H + tid]     = P.ab0[tid];
        S.s_w[2 * ATTN_H + tid] = P.ag[tid] * BN_INV;
        S.s_w[3 * ATTN_H + tid] = P.abeta[tid];
        S.s_w[4 * ATTN_H + tid] = P.aw1[tid];
    }
    if (tid == 0) S.s_w[5 * ATTN_H] = P.ab1[0];
    for (int j = tid; j < T; j += 256) S.t_s[j] = P.t[b * T + j];
    if (tid < STAT_H) {
        int c = tid;
        float acc = P.sb[c];
        #pragma unroll
        for (int k = 0; k < STAT_IN; ++k) acc += P.x_stat[b * STAT_IN + k] * P.sw[k * STAT_H + c];
        acc = acc * (P.sg[c] * BN_INV) + P.sbeta[c];
        S.xs_own[0][c] = lrelu(acc);
    }
    __syncthreads();
    #pragma unroll
    for (int l = 0; l < 2; ++l) {
        if (tid < STAT_H) {
            int c = tid;
            float a2 = P.lb_s[l * STAT_H + c];
            #pragma unroll
            for (int k = 0; k < STAT_H; ++k) a2 += S.xs_own[l][k] * P.lw_s[(l * STAT_H + k) * STAT_H + c];
            a2 = a2 * (P.lg_s[l * STAT_H + c] * BN_INV) + P.lbeta_s[l * STAT_H + c];
            S.xs_own[l + 1][c] = lrelu(a2);
        }
        __syncthreads();
    }
    float dtmax = 0.f;
    #pragma unroll
    for (int bb = 0; bb < B; ++bb)
        dtmax = fmaxf(dtmax, P.t[bb * T + (T - 1)] - P.t[bb * T]);
    *plen = P.lengths[b];
    return 1.0f / (dtmax + 1e-8f);
}

template <int STAGE>   // -1 = all (cooperative), 1..5 = single stage
__device__ __forceinline__ void run_all(const KP& P) {
    __shared__ Shm S;
    int tid = threadIdx.x;
    int lane = tid & 63, wave = tid >> 6;
    int blk = blockIdx.x;
    int b = blk >> 6, tile = blk & 63;
    int len;
    float inv_dt = preamble(P, S, b, tid, &len);
    if constexpr (STAGE == -1) {
        cg::grid_group g = cg::this_grid();
        mlp_stage(P, S, nullptr, P.XL, P.lw_t, P.lb_t, P.lg_t, P.lbeta_t, S.xs_own[0], b, tile, len, tid, true);
        __threadfence(); g.sync();
        attn_stage(P, S, P.XL, P.XT, inv_dt, b, tile, len, tid, lane, wave);
        __threadfence(); g.sync();
        mlp_stage(P, S, P.XT, P.XL,
                  P.lw_t + (TEMP_H + STAT_H) * TEMP_H, P.lb_t + TEMP_H, P.lg_t + TEMP_H, P.lbeta_t + TEMP_H,
                  S.xs_own[1], b, tile, len, tid, false);
        __threadfence(); g.sync();
        attn_stage(P, S, P.XL, P.XT, inv_dt, b, tile, len, tid, lane, wave);
        __threadfence(); g.sync();
        out_stage(P, S, b, tile, len, tid);
    } else if constexpr (STAGE == 1) {
        mlp_stage(P, S, nullptr, P.XL, P.lw_t, P.lb_t, P.lg_t, P.lbeta_t, S.xs_own[0], b, tile, len, tid, true);
    } else if constexpr (STAGE == 2) {
        attn_stage(P, S, P.XL, P.XT, inv_dt, b, tile, len, tid, lane, wave);
    } else if constexpr (STAGE == 3) {
        mlp_stage(P, S, P.XT, P.XL,
                  P.lw_t + (TEMP_H + STAT_H) * TEMP_H, P.lb_t + TEMP_H, P.lg_t + TEMP_H, P.lbeta_t + TEMP_H,
                  S.xs_own[1], b, tile, len, tid, false);
    } else if constexpr (STAGE == 4) {
        attn_stage(P, S, P.XL, P.XT, inv_dt, b, tile, len, tid, lane, wave);
    } else {
        out_stage(P, S, b, tile, len, tid);
    }
}

__global__ void __launch_bounds__(256, 2) k_coop(KP P) { run_all<-1>(P); }
template <int STAGE>
__global__ void __launch_bounds__(256, 2) k_stage(KP P) { run_all<STAGE>(P); }

extern "C" void kernel_launch(void* const* d_in, const int* in_sizes, int n_in,
                              void* d_out, int out_size, void* d_ws, size_t ws_size,
                              hipStream_t stream) {
    KP p;
    p.x_temp  = (const float*)d_in[0];
    p.x_stat  = (const float*)d_in[1];
    p.t       = (const float*)d_in[2];
    p.lengths = (const int*)d_in[4];
    p.aw0 = (const float*)d_in[5];
    p.ab0 = (const float*)d_in[6];
    p.ag  = (const float*)d_in[7];
    p.abeta = (const float*)d_in[8];
    p.aw1 = (const float*)d_in[9];
    p.ab1 = (const float*)d_in[10];
    p.tw  = (const float*)d_in[11];
    p.tb  = (const float*)d_in[12];
    p.tg  = (const float*)d_in[13];
    p.tbeta = (const float*)d_in[14];
    p.sw  = (const float*)d_in[15];
    p.sb  = (const float*)d_in[16];
    p.sg  = (const float*)d_in[17];
    p.sbeta = (const float*)d_in[18];
    p.lw_t = (const float*)d_in[19];
    p.lb_t = (const float*)d_in[20];
    p.lg_t = (const float*)d_in[21];
    p.lbeta_t = (const float*)d_in[22];
    p.lw_s = (const float*)d_in[23];
    p.lb_s = (const float*)d_in[24];
    p.lg_s = (const float*)d_in[25];
    p.lbeta_s = (const float*)d_in[26];
    p.cw = (const float*)d_in[27];
    p.cb = (const float*)d_in[28];

    float* ws = (float*)d_ws;
    p.XL = ws;                                   // B*T*64
    p.XT = ws + (size_t)B * T * TEMP_H;          // B*T*64
    p.out = (float*)d_out;
    p.outmax = p.out + (size_t)B * T * N_CLS;

    void* args[] = { (void*)&p };
    hipError_t err = hipLaunchCooperativeKernel((const void*)k_coop, dim3(GRID), dim3(256),
                                                args, 0, stream);
    if (err != hipSuccess) {
        (void)hipGetLastError();   // clear; deterministic fallback: 5 ordinary launches
        k_stage<1><<<GRID, 256, 0, stream>>>(p);
        k_stage<2><<<GRID, 256, 0, stream>>>(p);
        k_stage<3><<<GRID, 256, 0, stream>>>(p);
        k_stage<4><<<GRID, 256, 0, stream>>>(p);
        k_stage<5><<<GRID, 256, 0, stream>>>(p);
    }
}

// Round 4
// 160.187 us; speedup vs baseline: 3.0229x; 3.0229x over previous
//
#include <hip/hip_runtime.h>

#define B 8
#define T 512
#define TEMP_IN 32
#define STAT_IN 16
#define TEMP_H 64
#define STAT_H 32
#define ATTN_H 32
#define N_CLS 2
#define BN_INV 0.99999500003749969f
#define R 8   // query rows per attention tile

struct KP {
    const float *x_temp, *x_stat, *t;
    const int* lengths;
    const float *aw0, *ab0, *ag, *abeta, *aw1, *ab1;
    const float *tw, *tb, *tg, *tbeta;
    const float *sw, *sb, *sg, *sbeta;
    const float *lw_t, *lb_t, *lg_t, *lbeta_t;
    const float *lw_s, *lb_s, *lg_s, *lbeta_s;
    const float *cw, *cb;
    float *XL, *XL2;
    unsigned long long* slot;
    unsigned* cnt;
    float *out, *outmax;
};

__device__ __forceinline__ float lrelu(float x) {
    return fmaxf(x, 0.f) + 0.01f * fminf(x, 0.f);
}
__device__ __forceinline__ float wave_max(float x) {
    #pragma unroll
    for (int o = 32; o > 0; o >>= 1) x = fmaxf(x, __shfl_xor(x, o));
    return x;
}
__device__ __forceinline__ float wave_sum(float x) {
    #pragma unroll
    for (int o = 32; o > 0; o >>= 1) x += __shfl_xor(x, o);
    return x;
}
// monotone float -> uint32 (total order matches float compare)
__device__ __forceinline__ unsigned ordf(float f) {
    unsigned u = __float_as_uint(f);
    return (u & 0x80000000u) ? ~u : (u | 0x80000000u);
}

// ============ kernel 1: front MLP (encoder + layer0 mlp, row-local) ============
__global__ void __launch_bounds__(256) k_front(KP P) {
    int tid = threadIdx.x;
    int g = tid >> 6, c = tid & 63;
    int blk = blockIdx.x;
    int row0 = blk * 4;
    int b = row0 >> 9;
    __shared__ float xsA[STAT_H];
    __shared__ float xr[4][TEMP_IN];
    __shared__ float h0s[4][TEMP_H + STAT_H];

    if (blk == 0 && tid < 8) { P.slot[tid] = 0ULL; P.cnt[tid] = 0u; }

    // xs0 = stat encoder (layer-0 concat uses x_s BEFORE its first update)
    if (tid < STAT_H) {
        float acc = P.sb[tid];
        #pragma unroll
        for (int k = 0; k < STAT_IN; ++k) acc += P.x_stat[b * STAT_IN + k] * P.sw[k * STAT_H + tid];
        acc = acc * (P.sg[tid] * BN_INV) + P.sbeta[tid];
        xsA[tid] = lrelu(acc);
    }
    int row = row0 + g;
    int i = row & (T - 1);
    if (c < TEMP_IN) xr[g][c] = P.x_temp[row * TEMP_IN + c];
    __syncthreads();

    float acc = P.tb[c];
    #pragma unroll
    for (int k = 0; k < TEMP_IN; ++k) acc += xr[g][k] * P.tw[k * TEMP_H + c];
    acc = acc * (P.tg[c] * BN_INV) + P.tbeta[c];
    h0s[g][c] = lrelu(acc);
    if (c < STAT_H) h0s[g][TEMP_H + c] = xsA[c];
    __syncthreads();

    float a2 = P.lb_t[c];
    #pragma unroll
    for (int k = 0; k < TEMP_H + STAT_H; ++k) a2 += h0s[g][k] * P.lw_t[k * TEMP_H + c];
    a2 = a2 * (P.lg_t[c] * BN_INV) + P.lbeta_t[c];
    a2 = lrelu(a2);
    P.XL[(size_t)row * TEMP_H + c] = (i < P.lengths[b]) ? a2 : 0.f;
}

// ============ kernels 2/3: attention core + stage-specific epilogue ============
// MODE 0: attn over XL, epilogue = layer-1 MLP -> XL2
// MODE 1: attn over XL2, epilogue = classifier + out + atomic argmax + last-block outmax
template <int MODE>
__global__ void __launch_bounds__(256) k_attn_k(KP P) {
    __shared__ float att[R][T];               // 16 KB
    __shared__ float xi[R][TEMP_H];           // 2 KB
    __shared__ float part[4][R][TEMP_H];      // 8 KB
    __shared__ float x1[R][TEMP_H];           // 2 KB (attn output rows)
    __shared__ float t_s[T];                  // 2 KB
    __shared__ float s_w[5 * ATTN_H + 1];
    __shared__ float xsA[STAT_H], xsB[STAT_H];
    __shared__ float o_rc[R][2];

    int tid = threadIdx.x;
    int lane = tid & 63, wave = tid >> 6;
    int blk = blockIdx.x;
    int b = blk >> 6, tile = blk & 63, i0 = tile * R;
    const float* src = (MODE == 0) ? P.XL : P.XL2;

    // ---- preamble: temp-MLP weights, t row, xs chain ----
    if (tid < ATTN_H) {
        s_w[tid]              = P.aw0[tid];
        s_w[ATTN_H + tid]     = P.ab0[tid];
        s_w[2 * ATTN_H + tid] = P.ag[tid] * BN_INV;
        s_w[3 * ATTN_H + tid] = P.abeta[tid];
        s_w[4 * ATTN_H + tid] = P.aw1[tid];
    }
    if (tid == 0) s_w[5 * ATTN_H] = P.ab1[0];
    for (int j = tid; j < T; j += 256) t_s[j] = P.t[b * T + j];

    if (tid < STAT_H) {   // xs0
        float acc = P.sb[tid];
        #pragma unroll
        for (int k = 0; k < STAT_IN; ++k) acc += P.x_stat[b * STAT_IN + k] * P.sw[k * STAT_H + tid];
        acc = acc * (P.sg[tid] * BN_INV) + P.sbeta[tid];
        xsA[tid] = lrelu(acc);
    }
    __syncthreads();
    if (tid < STAT_H) {   // xs1
        float a2 = P.lb_s[tid];
        #pragma unroll
        for (int k = 0; k < STAT_H; ++k) a2 += xsA[k] * P.lw_s[k * STAT_H + tid];
        a2 = a2 * (P.lg_s[tid] * BN_INV) + P.lbeta_s[tid];
        xsB[tid] = lrelu(a2);
    }
    __syncthreads();
    if (MODE == 1) {
        if (tid < STAT_H) {   // xs2
            float a2 = P.lb_s[STAT_H + tid];
            #pragma unroll
            for (int k = 0; k < STAT_H; ++k) a2 += xsB[k] * P.lw_s[(STAT_H + k) * STAT_H + tid];
            a2 = a2 * (P.lg_s[STAT_H + tid] * BN_INV) + P.lbeta_s[STAT_H + tid];
            xsA[tid] = lrelu(a2);
        }
        __syncthreads();
    }
    const float* xs_l = (MODE == 1) ? xsA : xsB;

    float dtmax = 0.f;
    #pragma unroll
    for (int bb = 0; bb < B; ++bb)
        dtmax = fmaxf(dtmax, P.t[bb * T + (T - 1)] - P.t[bb * T]);
    float inv_dt = 1.0f / (dtmax + 1e-8f);
    int len = P.lengths[b];

    // ---- load own query rows ----
    for (int idx = tid; idx < R * TEMP_H; idx += 256)
        xi[idx >> 6][idx & 63] = src[((size_t)(b * T + i0 + (idx >> 6))) * TEMP_H + (idx & 63)];
    __syncthreads();

    // ---- phase 1: qk ----
    for (int j = tid; j < T; j += 256) {
        const float4* xj4 = reinterpret_cast<const float4*>(&src[((size_t)(b * T + j)) * TEMP_H]);
        float acc[R];
        #pragma unroll
        for (int r = 0; r < R; ++r) acc[r] = 0.f;
        #pragma unroll
        for (int c4 = 0; c4 < TEMP_H / 4; ++c4) {
            float4 xv = xj4[c4];
            #pragma unroll
            for (int r = 0; r < R; ++r) {
                acc[r] += xi[r][c4 * 4 + 0] * xv.x;
                acc[r] += xi[r][c4 * 4 + 1] * xv.y;
                acc[r] += xi[r][c4 * 4 + 2] * xv.z;
                acc[r] += xi[r][c4 * 4 + 3] * xv.w;
            }
        }
        #pragma unroll
        for (int r = 0; r < R; ++r) att[r][j] = acc[r] * 0.125f;
    }
    __syncthreads();

    // ---- phase 2: softmax(qk) + recomputed temp-attn softmax, combine, mask_j ----
    float ab1v = s_w[5 * ATTN_H];
    for (int rr = 0; rr < 2; ++rr) {
        int r = wave + rr * 4;
        int i = i0 + r;
        float ti = t_s[i];
        float v[8], dtq[8];
        float m = -1e30f;
        #pragma unroll
        for (int q = 0; q < 8; ++q) {
            int j = lane + q * 64;
            v[q] = att[r][j];
            m = fmaxf(m, v[q]);
            dtq[q] = (t_s[j] - ti) * inv_dt;
        }
        m = wave_max(m);
        float s = 0.f;
        #pragma unroll
        for (int q = 0; q < 8; ++q) { v[q] = expf(v[q] - m); s += v[q]; }
        s = wave_sum(s);
        float invs = 1.0f / s;
        float a[8];
        #pragma unroll
        for (int q = 0; q < 8; ++q) a[q] = ab1v;
        #pragma unroll 4
        for (int k = 0; k < ATTN_H; ++k) {
            float w0k = s_w[k];
            float b0k = s_w[ATTN_H + k];
            float gk  = s_w[2 * ATTN_H + k];
            float bbk = s_w[3 * ATTN_H + k];
            float w1k = s_w[4 * ATTN_H + k];
            #pragma unroll
            for (int q = 0; q < 8; ++q) {
                float h = dtq[q] * w0k + b0k;
                h = h * gk + bbk;
                h = fmaxf(h, 0.f) + 0.01f * fminf(h, 0.f);
                a[q] += h * w1k;
            }
        }
        float m2 = -1e30f;
        #pragma unroll
        for (int q = 0; q < 8; ++q) {
            int j = lane + q * 64;
            a[q] = (j < len) ? a[q] : -9e8f;
            m2 = fmaxf(m2, a[q]);
        }
        m2 = wave_max(m2);
        float s2 = 0.f;
        #pragma unroll
        for (int q = 0; q < 8; ++q) { a[q] = expf(a[q] - m2); s2 += a[q]; }
        s2 = wave_sum(s2);
        float inv2 = 1.0f / s2;
        #pragma unroll
        for (int q = 0; q < 8; ++q) {
            int j = lane + q * 64;
            att[r][j] = (j < len) ? (v[q] * invs + a[q] * inv2) : 0.f;
        }
    }
    __syncthreads();

    // ---- phase 3: PV ----
    float acc2[R];
    #pragma unroll
    for (int r = 0; r < R; ++r) acc2[r] = 0.f;
    for (int j = wave * 128; j < wave * 128 + 128; ++j) {
        float xv = src[((size_t)(b * T + j)) * TEMP_H + lane];
        #pragma unroll
        for (int r = 0; r < R; ++r) acc2[r] += att[r][j] * xv;
    }
    #pragma unroll
    for (int r = 0; r < R; ++r) part[wave][r][lane] = acc2[r];
    __syncthreads();
    for (int idx = tid; idx < R * TEMP_H; idx += 256) {
        int r = idx >> 6, cc = idx & 63;
        float sum = part[0][r][cc] + part[1][r][cc] + part[2][r][cc] + part[3][r][cc];
        int i = i0 + r;
        x1[r][cc] = (i < len) ? sum : 0.f;
    }
    __syncthreads();

    if (MODE == 0) {
        // ---- epilogue: layer-1 MLP on own rows (row-local), write XL2 ----
        const float* lw1    = P.lw_t + (TEMP_H + STAT_H) * TEMP_H;
        const float* lb1    = P.lb_t + TEMP_H;
        const float* lg1    = P.lg_t + TEMP_H;
        const float* lbeta1 = P.lbeta_t + TEMP_H;
        #pragma unroll
        for (int rr = 0; rr < 2; ++rr) {
            int r = wave * 2 + rr;
            int i = i0 + r;
            float acc = lb1[lane];
            #pragma unroll
            for (int k = 0; k < TEMP_H; ++k) acc += x1[r][k] * lw1[k * TEMP_H + lane];
            #pragma unroll
            for (int k = 0; k < STAT_H; ++k) acc += xs_l[k] * lw1[(TEMP_H + k) * TEMP_H + lane];
            acc = acc * (lg1[lane] * BN_INV) + lbeta1[lane];
            acc = lrelu(acc);
            P.XL2[((size_t)(b * T + i)) * TEMP_H + lane] = (i < len) ? acc : 0.f;
        }
    } else {
        // ---- epilogue: classifier, out writes, atomic argmax, last-block outmax ----
        if (tid < R * N_CLS) {
            int r = tid >> 1, cls = tid & 1;
            int i = i0 + r;
            float o = P.cb[cls];
            #pragma unroll
            for (int k = 0; k < TEMP_H; ++k) o += x1[r][k] * P.cw[k * N_CLS + cls];
            #pragma unroll
            for (int k = 0; k < STAT_H; ++k) o += xs_l[k] * P.cw[(TEMP_H + k) * N_CLS + cls];
            bool valid = i < len;
            if (!valid) o = 0.f;
            P.out[((size_t)(b * T + i)) * N_CLS + cls] = o;
            o_rc[r][cls] = o;
            __threadfence();   // release own out-store to device scope
        }
        __syncthreads();
        if (tid == 0) {
            for (int r = 0; r < R; ++r) {
                int i = i0 + r;
                bool valid = i < len;
                float diff = valid ? (o_rc[r][1] - o_rc[r][0]) : -1e30f;
                unsigned long long pack =
                    ((unsigned long long)ordf(diff) << 32) | (unsigned)(~(unsigned)i);
                atomicMax(&P.slot[b], pack);
            }
            __threadfence();
            unsigned old = atomicAdd(&P.cnt[b], 1u);
            if (old == 63u) {      // last tile of this batch: winner is final
                __threadfence();
                unsigned long long w = atomicMax(&P.slot[b], 0ULL);  // atomic read
                int idx = (int)(~(unsigned)(w & 0xffffffffu));
                P.outmax[b * 2 + 0] = P.out[((size_t)(b * T + idx)) * N_CLS + 0];
                P.outmax[b * 2 + 1] = P.out[((size_t)(b * T + idx)) * N_CLS + 1];
            }
        }
    }
}

extern "C" void kernel_launch(void* const* d_in, const int* in_sizes, int n_in,
                              void* d_out, int out_size, void* d_ws, size_t ws_size,
                              hipStream_t stream) {
    KP p;
    p.x_temp  = (const float*)d_in[0];
    p.x_stat  = (const float*)d_in[1];
    p.t       = (const float*)d_in[2];
    p.lengths = (const int*)d_in[4];
    p.aw0 = (const float*)d_in[5];
    p.ab0 = (const float*)d_in[6];
    p.ag  = (const float*)d_in[7];
    p.abeta = (const float*)d_in[8];
    p.aw1 = (const float*)d_in[9];
    p.ab1 = (const float*)d_in[10];
    p.tw  = (const float*)d_in[11];
    p.tb  = (const float*)d_in[12];
    p.tg  = (const float*)d_in[13];
    p.tbeta = (const float*)d_in[14];
    p.sw  = (const float*)d_in[15];
    p.sb  = (const float*)d_in[16];
    p.sg  = (const float*)d_in[17];
    p.sbeta = (const float*)d_in[18];
    p.lw_t = (const float*)d_in[19];
    p.lb_t = (const float*)d_in[20];
    p.lg_t = (const float*)d_in[21];
    p.lbeta_t = (const float*)d_in[22];
    p.lw_s = (const float*)d_in[23];
    p.lb_s = (const float*)d_in[24];
    p.lg_s = (const float*)d_in[25];
    p.lbeta_s = (const float*)d_in[26];
    p.cw = (const float*)d_in[27];
    p.cb = (const float*)d_in[28];

    float* ws = (float*)d_ws;
    p.XL  = ws;                                  // B*T*64
    p.XL2 = ws + (size_t)B * T * TEMP_H;         // B*T*64
    p.slot = (unsigned long long*)(ws + 2 * (size_t)B * T * TEMP_H);
    p.cnt  = (unsigned*)(p.slot + B);
    p.out = (float*)d_out;
    p.outmax = p.out + (size_t)B * T * N_CLS;

    k_front<<<B * T / 4, 256, 0, stream>>>(p);
    k_attn_k<0><<<B * (T / R), 256, 0, stream>>>(p);
    k_attn_k<1><<<B * (T / R), 256, 0, stream>>>(p);
}